// Round 5
// baseline (269.259 us; speedup 1.0000x reference)
//
#include <hip/hip_runtime.h>
#include <cstddef>

typedef __attribute__((ext_vector_type(8))) short bf16x8;     // MFMA A/B frag
typedef __attribute__((ext_vector_type(4))) float f32x4;      // MFMA C/D frag
typedef __attribute__((ext_vector_type(8))) unsigned short us8;

#define MFMA(a, b, c) __builtin_amdgcn_mfma_f32_16x16x32_bf16((a), (b), (c), 0, 0, 0)

#define KEXC 0.0450842200277256f   // log2(e)/32  -> exp(s/32) = exp2(s*KEXC)

__device__ __forceinline__ unsigned short f2bf(float f) {   // RNE
  union { float f; unsigned int u; } v; v.f = f;
  return (unsigned short)((v.u + 0x7FFFu + ((v.u >> 16) & 1u)) >> 16);
}
__device__ __forceinline__ float bf2f(unsigned short u) {
  union { unsigned int u; float f; } v; v.u = ((unsigned int)u) << 16; return v.f;
}
// pack two floats to bf16 pair, round-half-up
__device__ __forceinline__ unsigned int pack_bf2(float a, float b) {
  union { float f; unsigned int u; } x, y; x.f = a; y.f = b;
  return ((x.u + 0x8000u) >> 16) | ((y.u + 0x8000u) & 0xFFFF0000u);
}
// async global->LDS, 16B/lane; LDS dest = wave-uniform base + lane*16
__device__ __forceinline__ void glds16(const void* g, void* l) {
  __builtin_amdgcn_global_load_lds(
      (const __attribute__((address_space(1))) unsigned int*)g,
      (__attribute__((address_space(3))) unsigned int*)l, 16, 0, 0);
}

// ---------------------------------------------------------------------------
// prep: blocks [0,4096): cast X fp32->bf16 (1024 elems/block).
//       blocks [4096,4864): transpose+cast weights -> Wt[N][K] bf16.
//         +0..255: Wq; +256..511: Wk (scaled KEXC); +512..767: Wo.
// ---------------------------------------------------------------------------
__global__ __launch_bounds__(256) void prep(
    const float* __restrict__ X,  const float* __restrict__ Wq,
    const float* __restrict__ Wk, const float* __restrict__ Wo,
    unsigned short* __restrict__ Xbf, unsigned short* __restrict__ Wqkt,
    unsigned short* __restrict__ Wot)
{
  __shared__ __align__(16) unsigned short T[64 * 72];
  const int t = threadIdx.x;
  int blk = blockIdx.x;
  if (blk < 4096) {
    int i = (blk * 256 + t) * 4;
    float4 v = *(const float4*)&X[i];
    ushort4 o;
    o.x = f2bf(v.x); o.y = f2bf(v.y); o.z = f2bf(v.z); o.w = f2bf(v.w);
    *(ushort4*)&Xbf[i] = o;
    return;
  }
  blk -= 4096;
  const float* W; unsigned short* dst; int mode; float scale = 1.0f;
  if (blk < 256)      { W = Wq; dst = Wqkt;                 mode = 1; }
  else if (blk < 512) { W = Wk; dst = Wqkt + 1024 * 1024;   mode = 1; scale = KEXC; blk -= 256; }
  else                { W = Wo; dst = Wot;                  mode = 0; blk -= 512; }
  const int K = 1024, N = 1024;
  const int n0 = (blk & 15) * 64, k0 = (blk >> 4) * 64;
  const int kr = t >> 4, n4 = (t & 15) * 4;
  #pragma unroll
  for (int i = 0; i < 4; ++i) {
    const int k = k0 + kr + i * 16;
    const float* src = (mode == 0) ? &W[(size_t)k * N + n0 + n4]
                                   : &W[((size_t)(n0 >> 6) * K + k) * 64 + n4];
    float4 v = *(const float4*)src;
    T[(n4 + 0) * 72 + kr + i * 16] = f2bf(v.x * scale);
    T[(n4 + 1) * 72 + kr + i * 16] = f2bf(v.y * scale);
    T[(n4 + 2) * 72 + kr + i * 16] = f2bf(v.z * scale);
    T[(n4 + 3) * 72 + kr + i * 16] = f2bf(v.w * scale);
  }
  __syncthreads();
  const int n = t >> 2, kc = (t & 3) * 16;
  us8 o0 = *(const us8*)&T[n * 72 + kc];
  us8 o1 = *(const us8*)&T[n * 72 + kc + 8];
  *(us8*)&dst[(size_t)(n0 + n) * K + k0 + kc] = o0;
  *(us8*)&dst[(size_t)(n0 + n) * K + k0 + kc + 8] = o1;
}

// ---------------------------------------------------------------------------
// m97-style MFMA GEMM: C[m,n] = sum_k A[m,k]*Bt[n,k] + bias.
// SPLIT=1: N=2048, bf16 out; cols<1024 -> out0+bias0; else out1+bias1*bs1.
// SPLIT=0: fp32 out -> out0+bias0.
// ---------------------------------------------------------------------------
template<int SPLIT>
__global__ __launch_bounds__(256) void gemm_m97(
    const unsigned short* __restrict__ A, const unsigned short* __restrict__ Bt,
    const float* __restrict__ bias0, const float* __restrict__ bias1,
    void* __restrict__ out0, void* __restrict__ out1, int N, int K, float bs1)
{
  __shared__ __align__(16) unsigned short Asl[128 * 32];
  __shared__ __align__(16) unsigned short Bsl[128 * 32];
  const int tid = threadIdx.x;
  const int m0 = blockIdx.y * 128, n0 = blockIdx.x * 128;
  const int wave = tid >> 6, lane = tid & 63;
  const int wm = (wave & 1) * 64, wn = (wave >> 1) * 64;
  const int l15 = lane & 15, l4 = lane >> 4;
  const int srow = tid >> 2, scol = (tid & 3) * 8;
  const unsigned short* ga = &A[(size_t)(m0 + srow) * K + scol];
  const unsigned short* gb = &Bt[(size_t)(n0 + srow) * K + scol];
  const size_t half = (size_t)64 * K;

  f32x4 acc[4][4] = {};
  for (int kt = 0; kt < K; kt += 32) {
    __syncthreads();
    glds16(ga + kt,        &Asl[tid * 8]);
    glds16(ga + half + kt, &Asl[(tid + 256) * 8]);
    glds16(gb + kt,        &Bsl[tid * 8]);
    glds16(gb + half + kt, &Bsl[(tid + 256) * 8]);
    __syncthreads();
    bf16x8 af[4], bfv[4];
    #pragma unroll
    for (int mi = 0; mi < 4; ++mi)
      af[mi] = *(const bf16x8*)&Asl[(wm + mi * 16 + l15) * 32 + l4 * 8];
    #pragma unroll
    for (int nj = 0; nj < 4; ++nj)
      bfv[nj] = *(const bf16x8*)&Bsl[(wn + nj * 16 + l15) * 32 + l4 * 8];
    #pragma unroll
    for (int mi = 0; mi < 4; ++mi)
      #pragma unroll
      for (int nj = 0; nj < 4; ++nj)
        acc[mi][nj] = MFMA(af[mi], bfv[nj], acc[mi][nj]);
  }

  #pragma unroll
  for (int mi = 0; mi < 4; ++mi) {
    #pragma unroll
    for (int nj = 0; nj < 4; ++nj) {
      const int row = m0 + wm + mi * 16 + l4 * 4;
      const int col = n0 + wn + nj * 16 + l15;
      if (SPLIT) {
        const int qside = (col < 1024);
        const int lc = qside ? col : col - 1024;
        const float bv = qside ? bias0[lc] : bias1[lc] * bs1;
        unsigned short* dst = qside ? (unsigned short*)out0 : (unsigned short*)out1;
        #pragma unroll
        for (int r = 0; r < 4; ++r)
          dst[(size_t)(row + r) * 1024 + lc] = f2bf(acc[mi][nj][r] + bv);
      } else {
        const float bv = bias0[col];
        #pragma unroll
        for (int r = 0; r < 4; ++r)
          ((float*)out0)[(size_t)(row + r) * N + col] = acc[mi][nj][r] + bv;
      }
    }
  }
}

// ---------------------------------------------------------------------------
// cs_vt v2: per (bh, k-tile64): L[k] = sum_q exp2(K'[k,:].Q[q,:]), then
//           Vt[bh*64+d][k] = Q[k,d]/L[k].
// BARRIER-FREE main loop: all MFMA fragments loaded global->VGPR directly
// (every operand is 16B-contiguous per lane). One barrier total (Vt transpose).
// grid(x=64 bh, y=16 ktile) -> same-bh on same XCD.
// ---------------------------------------------------------------------------
__global__ __launch_bounds__(256) void cs_vt(
    const unsigned short* __restrict__ Qb, const unsigned short* __restrict__ Kb,
    unsigned short* __restrict__ Vt)
{
  const int S = 1024, E = 1024;
  __shared__ __align__(16) unsigned short T[64 * 72];
  __shared__ float Ls[64];
  const int bh = blockIdx.x, b = bh >> 4, h = bh & 15;
  const int k0 = blockIdx.y * 64;
  const int tid = threadIdx.x, wave = tid >> 6, lane = tid & 63;
  const int l15 = lane & 15, l4 = lane >> 4;
  const size_t rowBase = (size_t)b * S;
  const unsigned short* gQ = &Qb[rowBase * E + h * 64 + l4 * 8];
  const unsigned short* gK = &Kb[rowBase * E + h * 64 + l4 * 8];

  // K A-frags for this wave's 16 k-rows (resident)
  bf16x8 ak[2];
  #pragma unroll
  for (int ds = 0; ds < 2; ++ds)
    ak[ds] = *(const bf16x8*)&gK[(size_t)(k0 + wave * 16 + l15) * E + ds * 32];

  float Lacc[4] = {};
  for (int qc = 0; qc < 8; ++qc) {
    bf16x8 bq[8][2];
    #pragma unroll
    for (int nj = 0; nj < 8; ++nj)
      #pragma unroll
      for (int ds = 0; ds < 2; ++ds)
        bq[nj][ds] = *(const bf16x8*)&gQ[(size_t)(qc * 128 + nj * 16 + l15) * E + ds * 32];
    f32x4 accs[8] = {};
    #pragma unroll
    for (int ds = 0; ds < 2; ++ds)
      #pragma unroll
      for (int nj = 0; nj < 8; ++nj)
        accs[nj] = MFMA(ak[ds], bq[nj][ds], accs[nj]);
    #pragma unroll
    for (int nj = 0; nj < 8; ++nj)
      #pragma unroll
      for (int rr = 0; rr < 4; ++rr)
        Lacc[rr] += __builtin_amdgcn_exp2f(accs[nj][rr]);
  }
  #pragma unroll
  for (int off = 1; off < 16; off <<= 1)
    #pragma unroll
    for (int rr = 0; rr < 4; ++rr)
      Lacc[rr] += __shfl_xor(Lacc[rr], off);
  if (l15 == 0) {
    #pragma unroll
    for (int rr = 0; rr < 4; ++rr)
      Ls[wave * 16 + l4 * 4 + rr] = Lacc[rr];
  }
  __syncthreads();

  // Vt build: load Q rows [k0,k0+64), scale by 1/L, transpose via LDS
  const int row = tid >> 2, d16 = (tid & 3) * 16;
  const float rl = 1.0f / Ls[row];
  const unsigned short* src = &Qb[(rowBase + k0 + row) * E + h * 64 + d16];
  us8 v0 = *(const us8*)src, v1 = *(const us8*)(src + 8);
  #pragma unroll
  for (int j = 0; j < 8; ++j) T[(d16 + j) * 72 + row]     = f2bf(bf2f(v0[j]) * rl);
  #pragma unroll
  for (int j = 0; j < 8; ++j) T[(d16 + 8 + j) * 72 + row] = f2bf(bf2f(v1[j]) * rl);
  __syncthreads();
  const int d = tid >> 2, kh = (tid & 3) * 16;
  unsigned short* dst = &Vt[((size_t)bh * 64 + d) * S + k0 + kh];
  *(us8*)dst       = *(const us8*)&T[d * 72 + kh];
  *(us8*)(dst + 8) = *(const us8*)&T[d * 72 + kh + 8];
}

// ---------------------------------------------------------------------------
// attn_out v2: per (bh, q-tile128): stream 16 k-tiles of 64.
// BARRIER-FREE: K/V/Q fragments loaded global->VGPR directly; only the
// wave-private Ps C->A layout round-trip uses LDS (lgkmcnt-ordered, no sync).
// S arrives pre-scaled (K' = KEXC*K) -> exp2 is raw v_exp_f32.
// grid(x=64 bh, y=8 qtile) -> same-bh on same XCD.  LDS 16 KB.
// ---------------------------------------------------------------------------
__global__ __launch_bounds__(256) void attn_out(
    const unsigned short* __restrict__ Qb, const unsigned short* __restrict__ Kb,
    const unsigned short* __restrict__ VtH, unsigned short* __restrict__ O)
{
  const int S = 1024, E = 1024;
  __shared__ __align__(16) unsigned short Ps[2][128 * 32];   // [khalf][q][k]
  const int bh = blockIdx.x, b = bh >> 4, h = bh & 15;
  const int q0 = blockIdx.y * 128;
  const int tid = threadIdx.x, wave = tid >> 6, lane = tid & 63;
  const int l15 = lane & 15, l4 = lane >> 4;
  const size_t rowBase = (size_t)b * S;
  const unsigned short* gQ = &Qb[(rowBase + q0) * E + h * 64 + l4 * 8];
  const unsigned short* gK = &Kb[rowBase * E + h * 64 + l4 * 8];
  const unsigned short* gV = &VtH[(size_t)bh * 64 * S + l4 * 8];

  // Q B-frags (resident): q = wave*32 + nj2*16 + l15
  bf16x8 bq[2][2];
  #pragma unroll
  for (int nj2 = 0; nj2 < 2; ++nj2)
    #pragma unroll
    for (int ds = 0; ds < 2; ++ds)
      bq[nj2][ds] = *(const bf16x8*)&gQ[(size_t)(wave * 32 + nj2 * 16 + l15) * E + ds * 32];

  f32x4 acco[2][4] = {};
  for (int it = 0; it < 16; ++it) {
    const int k0 = it * 64;
    // K A-frags + V B-frags, direct from global (L1 filters 4-wave redundancy)
    bf16x8 ak[4][2], bv[4][2];
    #pragma unroll
    for (int mi = 0; mi < 4; ++mi)
      #pragma unroll
      for (int ds = 0; ds < 2; ++ds)
        ak[mi][ds] = *(const bf16x8*)&gK[(size_t)(k0 + mi * 16 + l15) * E + ds * 32];
    #pragma unroll
    for (int nj = 0; nj < 4; ++nj)
      #pragma unroll
      for (int ks = 0; ks < 2; ++ks)
        bv[nj][ks] = *(const bf16x8*)&gV[(size_t)(nj * 16 + l15) * S + k0 + ks * 32];

    // S^T-GEMM: C[m=k][n=q] -> lane holds 4 contiguous k at fixed q
    f32x4 accs[4][2] = {};
    #pragma unroll
    for (int ds = 0; ds < 2; ++ds)
      #pragma unroll
      for (int mi = 0; mi < 4; ++mi)
        #pragma unroll
        for (int nj2 = 0; nj2 < 2; ++nj2)
          accs[mi][nj2] = MFMA(ak[mi][ds], bq[nj2][ds], accs[mi][nj2]);

    // P = exp2(s) -> wave-private Ps rows [32*wave, 32*wave+32)
    #pragma unroll
    for (int mi = 0; mi < 4; ++mi) {
      #pragma unroll
      for (int nj2 = 0; nj2 < 2; ++nj2) {
        const int q = wave * 32 + nj2 * 16 + l15;
        uint2 pk;
        pk.x = pack_bf2(__builtin_amdgcn_exp2f(accs[mi][nj2][0]),
                        __builtin_amdgcn_exp2f(accs[mi][nj2][1]));
        pk.y = pack_bf2(__builtin_amdgcn_exp2f(accs[mi][nj2][2]),
                        __builtin_amdgcn_exp2f(accs[mi][nj2][3]));
        *(uint2*)&Ps[mi >> 1][q * 32 + (mi & 1) * 16 + l4 * 4] = pk;
      }
    }
    // O-GEMM (same-wave Ps write->read ordered by lgkmcnt; no barrier)
    #pragma unroll
    for (int ks = 0; ks < 2; ++ks) {
      #pragma unroll
      for (int nj2 = 0; nj2 < 2; ++nj2) {
        bf16x8 ap = *(const bf16x8*)&Ps[ks][(wave * 32 + nj2 * 16 + l15) * 32 + l4 * 8];
        #pragma unroll
        for (int nj = 0; nj < 4; ++nj)
          acco[nj2][nj] = MFMA(ap, bv[nj][ks], acco[nj2][nj]);
      }
    }
  }

  #pragma unroll
  for (int nj2 = 0; nj2 < 2; ++nj2)
    #pragma unroll
    for (int nj = 0; nj < 4; ++nj)
      #pragma unroll
      for (int rr = 0; rr < 4; ++rr)
        O[(rowBase + q0 + wave * 32 + nj2 * 16 + l4 * 4 + rr) * E + h * 64 + nj * 16 + l15] =
            f2bf(acco[nj2][nj][rr]);
}

// ---------------------------------------------------------------------------
// inputs: 0=X 1=W_q 2=b_q 3=W_k 4=b_k 5=W_v 6=b_v 7=W_o 8=b_o
// ws (bf16): Xbf[4M] Wqkt[2M] Wot[1M] Qb[4M] Kb[4M] Ob[4M] Vt[4M]  (~46 MB)
// ---------------------------------------------------------------------------
extern "C" void kernel_launch(void* const* d_in, const int* in_sizes, int n_in,
                              void* d_out, int out_size, void* d_ws, size_t ws_size,
                              hipStream_t stream)
{
  const float* X  = (const float*)d_in[0];
  const float* Wq = (const float*)d_in[1];
  const float* bq = (const float*)d_in[2];
  const float* Wk = (const float*)d_in[3];
  const float* bk = (const float*)d_in[4];
  const float* Wo = (const float*)d_in[7];
  const float* bo = (const float*)d_in[8];

  const int Mr = 4096, E = 1024;
  unsigned short* Xbf  = (unsigned short*)d_ws;
  unsigned short* Wqkt = Xbf  + (size_t)Mr * E;
  unsigned short* Wot  = Wqkt + (size_t)2 * E * E;
  unsigned short* Qb   = Wot  + (size_t)E * E;
  unsigned short* Kb   = Qb   + (size_t)Mr * E;
  unsigned short* Ob   = Kb   + (size_t)Mr * E;
  unsigned short* Vt   = Ob   + (size_t)Mr * E;

  prep<<<dim3(4864), dim3(256), 0, stream>>>(X, Wq, Wk, Wo, Xbf, Wqkt, Wot);

  // fused Q|K' projection (K' = KEXC-scaled)
  gemm_m97<1><<<dim3(16, 32), dim3(256), 0, stream>>>(
      Xbf, Wqkt, bq, bk, (void*)Qb, (void*)Kb, 2048, E, KEXC);

  cs_vt<<<dim3(64, 16), dim3(256), 0, stream>>>(Qb, Kb, Vt);
  attn_out<<<dim3(64, 8), dim3(256), 0, stream>>>(Qb, Kb, Vt, Ob);

  gemm_m97<0><<<dim3(8, 32), dim3(256), 0, stream>>>(
      Ob, Wot, bo, nullptr, d_out, nullptr, E, E, 1.0f);
}

// Round 6
// 197.622 us; speedup vs baseline: 1.3625x; 1.3625x over previous
//
#include <hip/hip_runtime.h>
#include <cstddef>

typedef __attribute__((ext_vector_type(8))) short bf16x8;     // MFMA A/B frag
typedef __attribute__((ext_vector_type(4))) float f32x4;      // MFMA C/D frag
typedef __attribute__((ext_vector_type(8))) unsigned short us8;

#define MFMA(a, b, c) __builtin_amdgcn_mfma_f32_16x16x32_bf16((a), (b), (c), 0, 0, 0)

#define KEXC 0.0450842200277256f   // log2(e)/32  -> exp(s/32) = exp2(s*KEXC)

__device__ __forceinline__ unsigned short f2bf(float f) {   // RNE
  union { float f; unsigned int u; } v; v.f = f;
  return (unsigned short)((v.u + 0x7FFFu + ((v.u >> 16) & 1u)) >> 16);
}
__device__ __forceinline__ float bf2f(unsigned short u) {
  union { unsigned int u; float f; } v; v.u = ((unsigned int)u) << 16; return v.f;
}
// pack two floats to bf16 pair, round-half-up
__device__ __forceinline__ unsigned int pack_bf2(float a, float b) {
  union { float f; unsigned int u; } x, y; x.f = a; y.f = b;
  return ((x.u + 0x8000u) >> 16) | ((y.u + 0x8000u) & 0xFFFF0000u);
}
// async global->LDS, 16B/lane; LDS dest = wave-uniform base + lane*16
__device__ __forceinline__ void glds16(const void* g, void* l) {
  __builtin_amdgcn_global_load_lds(
      (const __attribute__((address_space(1))) unsigned int*)g,
      (__attribute__((address_space(3))) unsigned int*)l, 16, 0, 0);
}

// ---------------------------------------------------------------------------
// prep: blocks [0,4096): cast X fp32->bf16 (1024 elems/block).
//       blocks [4096,4864): transpose+cast weights -> Wt[N][K] bf16.
//         +0..255: Wq; +256..511: Wk (scaled KEXC); +512..767: Wo.
// ---------------------------------------------------------------------------
__global__ __launch_bounds__(256) void prep(
    const float* __restrict__ X,  const float* __restrict__ Wq,
    const float* __restrict__ Wk, const float* __restrict__ Wo,
    unsigned short* __restrict__ Xbf, unsigned short* __restrict__ Wqkt,
    unsigned short* __restrict__ Wot)
{
  __shared__ __align__(16) unsigned short T[64 * 72];
  const int t = threadIdx.x;
  int blk = blockIdx.x;
  if (blk < 4096) {
    int i = (blk * 256 + t) * 4;
    float4 v = *(const float4*)&X[i];
    ushort4 o;
    o.x = f2bf(v.x); o.y = f2bf(v.y); o.z = f2bf(v.z); o.w = f2bf(v.w);
    *(ushort4*)&Xbf[i] = o;
    return;
  }
  blk -= 4096;
  const float* W; unsigned short* dst; int mode; float scale = 1.0f;
  if (blk < 256)      { W = Wq; dst = Wqkt;                 mode = 1; }
  else if (blk < 512) { W = Wk; dst = Wqkt + 1024 * 1024;   mode = 1; scale = KEXC; blk -= 256; }
  else                { W = Wo; dst = Wot;                  mode = 0; blk -= 512; }
  const int K = 1024, N = 1024;
  const int n0 = (blk & 15) * 64, k0 = (blk >> 4) * 64;
  const int kr = t >> 4, n4 = (t & 15) * 4;
  #pragma unroll
  for (int i = 0; i < 4; ++i) {
    const int k = k0 + kr + i * 16;
    const float* src = (mode == 0) ? &W[(size_t)k * N + n0 + n4]
                                   : &W[((size_t)(n0 >> 6) * K + k) * 64 + n4];
    float4 v = *(const float4*)src;
    T[(n4 + 0) * 72 + kr + i * 16] = f2bf(v.x * scale);
    T[(n4 + 1) * 72 + kr + i * 16] = f2bf(v.y * scale);
    T[(n4 + 2) * 72 + kr + i * 16] = f2bf(v.z * scale);
    T[(n4 + 3) * 72 + kr + i * 16] = f2bf(v.w * scale);
  }
  __syncthreads();
  const int n = t >> 2, kc = (t & 3) * 16;
  us8 o0 = *(const us8*)&T[n * 72 + kc];
  us8 o1 = *(const us8*)&T[n * 72 + kc + 8];
  *(us8*)&dst[(size_t)(n0 + n) * K + k0 + kc] = o0;
  *(us8*)&dst[(size_t)(n0 + n) * K + k0 + kc + 8] = o1;
}

// ---------------------------------------------------------------------------
// m97-style MFMA GEMM: C[m,n] = sum_k A[m,k]*Bt[n,k] + bias.
// SPLIT=1: N=2048, bf16 out; col tile uniform per block (1024 % 128 == 0):
//          n0<1024 -> out0+bias0; else out1+bias1*bs1.
// SPLIT=0: fp32 out -> out0+bias0.
// ---------------------------------------------------------------------------
template<int SPLIT>
__global__ __launch_bounds__(256) void gemm_m97(
    const unsigned short* __restrict__ A, const unsigned short* __restrict__ Bt,
    const float* __restrict__ bias0, const float* __restrict__ bias1,
    void* __restrict__ out0, void* __restrict__ out1, int N, int K, float bs1)
{
  __shared__ __align__(16) unsigned short Asl[128 * 32];
  __shared__ __align__(16) unsigned short Bsl[128 * 32];
  const int tid = threadIdx.x;
  const int m0 = blockIdx.y * 128, n0 = blockIdx.x * 128;
  const int wave = tid >> 6, lane = tid & 63;
  const int wm = (wave & 1) * 64, wn = (wave >> 1) * 64;
  const int l15 = lane & 15, l4 = lane >> 4;
  const int srow = tid >> 2, scol = (tid & 3) * 8;
  const unsigned short* ga = &A[(size_t)(m0 + srow) * K + scol];
  const unsigned short* gb = &Bt[(size_t)(n0 + srow) * K + scol];
  const size_t half = (size_t)64 * K;

  f32x4 acc[4][4] = {};
  for (int kt = 0; kt < K; kt += 32) {
    __syncthreads();
    glds16(ga + kt,        &Asl[tid * 8]);
    glds16(ga + half + kt, &Asl[(tid + 256) * 8]);
    glds16(gb + kt,        &Bsl[tid * 8]);
    glds16(gb + half + kt, &Bsl[(tid + 256) * 8]);
    __syncthreads();
    bf16x8 af[4], bfv[4];
    #pragma unroll
    for (int mi = 0; mi < 4; ++mi)
      af[mi] = *(const bf16x8*)&Asl[(wm + mi * 16 + l15) * 32 + l4 * 8];
    #pragma unroll
    for (int nj = 0; nj < 4; ++nj)
      bfv[nj] = *(const bf16x8*)&Bsl[(wn + nj * 16 + l15) * 32 + l4 * 8];
    #pragma unroll
    for (int mi = 0; mi < 4; ++mi)
      #pragma unroll
      for (int nj = 0; nj < 4; ++nj)
        acc[mi][nj] = MFMA(af[mi], bfv[nj], acc[mi][nj]);
  }

  const int qside = SPLIT ? (n0 < 1024) : 1;
  const float* bias = (SPLIT && !qside) ? bias1 : bias0;
  const float bscale = (SPLIT && !qside) ? bs1 : 1.0f;
  unsigned short* dstb = (SPLIT && !qside) ? (unsigned short*)out1 : (unsigned short*)out0;
  const int ncol0 = (SPLIT && !qside) ? n0 - 1024 : n0;
  #pragma unroll
  for (int mi = 0; mi < 4; ++mi) {
    #pragma unroll
    for (int nj = 0; nj < 4; ++nj) {
      const int row = m0 + wm + mi * 16 + l4 * 4;
      const int col = ncol0 + wn + nj * 16 + l15;
      const float bv = bias[col] * bscale;
      #pragma unroll
      for (int r = 0; r < 4; ++r) {
        const float v = acc[mi][nj][r] + bv;
        if (SPLIT) dstb[(size_t)(row + r) * 1024 + col] = f2bf(v);
        else       ((float*)out0)[(size_t)(row + r) * N + col] = v;
      }
    }
  }
}

// ---------------------------------------------------------------------------
// cs_vt: per (bh, k-tile64): L[k] = sum_q exp2(K'[k,:].Q[q,:]), then
//        Vt[bh*64+d][k] = Q[k,d]/L[k]  (bf16, k contiguous).
// K-frags resident in VGPRs (one-time load); Q staged glds double-buffered.
// T transpose buffer ALIASES the Q pool (reads done by then). LDS 32.25 KB
// -> 4 blocks/CU, matching the 1024-block grid.
// ---------------------------------------------------------------------------
__global__ __launch_bounds__(256) void cs_vt(
    const unsigned short* __restrict__ Qb, const unsigned short* __restrict__ Kb,
    unsigned short* __restrict__ Vt)
{
  const int S = 1024, E = 1024;
  __shared__ __align__(16) unsigned short pool[16384];   // Qs[2][2][128*32]; T aliases
  __shared__ float Ls[64];
  const int bh = blockIdx.x, b = bh >> 4, h = bh & 15;
  const int k0 = blockIdx.y * 64;
  const int tid = threadIdx.x, wave = tid >> 6, lane = tid & 63;
  const int l15 = lane & 15, l4 = lane >> 4;
  const size_t rowBase = (size_t)b * S;
  const int srow = tid >> 2, scol = (tid & 3) * 8;
  const unsigned short* gQs = &Qb[(rowBase + srow) * E + h * 64 + scol];
  #define QS(buf, ds) (pool + (buf) * 8192 + (ds) * 4096)

  // resident K' A-frags for this wave's 16 k-rows (one-time global load)
  bf16x8 ak[2];
  #pragma unroll
  for (int ds = 0; ds < 2; ++ds)
    ak[ds] = *(const bf16x8*)&Kb[(rowBase + k0 + wave * 16 + l15) * E + h * 64 + ds * 32 + l4 * 8];

  #pragma unroll
  for (int ds = 0; ds < 2; ++ds) {
    glds16(gQs + (size_t)0 * E  + ds * 32, QS(0, ds) + tid * 8);
    glds16(gQs + (size_t)64 * E + ds * 32, QS(0, ds) + (tid + 256) * 8);
  }

  float Lacc[4] = {};
  for (int it = 0; it < 8; ++it) {
    const int cur = it & 1;
    __syncthreads();             // Qs[cur] staged; prior reads of Qs[1-cur] done
    if (it < 7) {
      const size_t q1 = (size_t)(it + 1) * 128;
      #pragma unroll
      for (int ds = 0; ds < 2; ++ds) {
        glds16(gQs + q1 * E        + ds * 32, QS(1 - cur, ds) + tid * 8);
        glds16(gQs + (q1 + 64) * E + ds * 32, QS(1 - cur, ds) + (tid + 256) * 8);
      }
    }
    f32x4 accs[8] = {};
    #pragma unroll
    for (int ds = 0; ds < 2; ++ds)
      #pragma unroll
      for (int nj = 0; nj < 8; ++nj) {
        bf16x8 bv = *(const bf16x8*)&QS(cur, ds)[(nj * 16 + l15) * 32 + l4 * 8];
        accs[nj] = MFMA(ak[ds], bv, accs[nj]);
      }
    #pragma unroll
    for (int nj = 0; nj < 8; ++nj)
      #pragma unroll
      for (int rr = 0; rr < 4; ++rr)
        Lacc[rr] += __builtin_amdgcn_exp2f(accs[nj][rr]);
  }
  #pragma unroll
  for (int off = 1; off < 16; off <<= 1)
    #pragma unroll
    for (int rr = 0; rr < 4; ++rr)
      Lacc[rr] += __shfl_xor(Lacc[rr], off);
  if (l15 == 0) {
    #pragma unroll
    for (int rr = 0; rr < 4; ++rr)
      Ls[wave * 16 + l4 * 4 + rr] = Lacc[rr];
  }
  __syncthreads();   // Ls ready; all Qs reads done -> pool reusable as T

  unsigned short* T = pool;   // 64*72 = 4608 ushorts, fits in pool
  const int row = tid >> 2, d16 = (tid & 3) * 16;
  const float rl = 1.0f / Ls[row];
  const unsigned short* src = &Qb[(rowBase + k0 + row) * E + h * 64 + d16];
  us8 v0 = *(const us8*)src, v1 = *(const us8*)(src + 8);
  #pragma unroll
  for (int j = 0; j < 8; ++j) T[(d16 + j) * 72 + row]     = f2bf(bf2f(v0[j]) * rl);
  #pragma unroll
  for (int j = 0; j < 8; ++j) T[(d16 + 8 + j) * 72 + row] = f2bf(bf2f(v1[j]) * rl);
  __syncthreads();
  const int d = tid >> 2, kh = (tid & 3) * 16;
  unsigned short* dst = &Vt[((size_t)bh * 64 + d) * S + k0 + kh];
  *(us8*)dst       = *(const us8*)&T[d * 72 + kh];
  *(us8*)(dst + 8) = *(const us8*)&T[d * 72 + kh + 8];
  #undef QS
}

// ---------------------------------------------------------------------------
// attn_out: per (bh, q-tile128): stream 16 k-tiles of 64, SOFTWARE-PIPELINED:
//   iter it:  S-GEMM(it) -> O-GEMM(it-1) -> exp2/write Ps(it)
// Ps double-buffered (write->read distance = 1 full iter, wave-private, no
// barrier), Vs TRIPLE-buffered (O-GEMM(it-1) reads tile it-1 while prefetch
// writes tile it+1), Ks double-buffered. Ps row stride 40 ushorts (80 B):
// ds_write_b64 2-way instead of 8-way conflicts. Q-frags resident in VGPRs.
// One barrier/iter; prefetch issued after it. LDS 80 KB -> 2 blocks/CU
// (grid is 2/CU anyway). grid(x=64 bh, y=8 qtile).
// ---------------------------------------------------------------------------
__global__ __launch_bounds__(256) void attn_out(
    const unsigned short* __restrict__ Qb, const unsigned short* __restrict__ Kb,
    const unsigned short* __restrict__ VtH, unsigned short* __restrict__ O)
{
  const int S = 1024, E = 1024;
  __shared__ __align__(16) unsigned short Ksb[2][2][64 * 32];   // [buf][dhalf]
  __shared__ __align__(16) unsigned short Vsb[3][2][64 * 32];   // [buf][khalf]
  __shared__ __align__(16) unsigned short Psb[2][2][128 * 40];  // [buf][khalf]
  const int bh = blockIdx.x, b = bh >> 4, h = bh & 15;
  const int q0 = blockIdx.y * 128;
  const int tid = threadIdx.x, wave = tid >> 6, lane = tid & 63;
  const int l15 = lane & 15, l4 = lane >> 4;
  const size_t rowBase = (size_t)b * S;
  const int srow = tid >> 2, scol = (tid & 3) * 8;
  const unsigned short* gK = &Kb[(rowBase + srow) * E + h * 64 + scol];
  const unsigned short* gV = &VtH[((size_t)bh * 64 + srow) * S + scol];

  // resident Q B-frags (one-time global load): q = wave*32 + nj2*16 + l15
  bf16x8 bq[2][2];
  #pragma unroll
  for (int nj2 = 0; nj2 < 2; ++nj2)
    #pragma unroll
    for (int ds = 0; ds < 2; ++ds)
      bq[nj2][ds] = *(const bf16x8*)&Qb[(rowBase + q0 + wave * 32 + nj2 * 16 + l15) * E
                                        + h * 64 + ds * 32 + l4 * 8];

  // stage tile 0
  glds16(gK,      &Ksb[0][0][tid * 8]);
  glds16(gK + 32, &Ksb[0][1][tid * 8]);
  glds16(gV,      &Vsb[0][0][tid * 8]);
  glds16(gV + 32, &Vsb[0][1][tid * 8]);

  f32x4 acco[2][4] = {};
  f32x4 accs[4][2];

  #define SGEMM(KBUF)                                                          \
    {                                                                          \
      _Pragma("unroll")                                                        \
      for (int mi = 0; mi < 4; ++mi)                                           \
        _Pragma("unroll")                                                      \
        for (int nj2 = 0; nj2 < 2; ++nj2) accs[mi][nj2] = (f32x4){};           \
      _Pragma("unroll")                                                        \
      for (int ds = 0; ds < 2; ++ds)                                           \
        _Pragma("unroll")                                                      \
        for (int mi = 0; mi < 4; ++mi) {                                       \
          bf16x8 ak = *(const bf16x8*)&Ksb[KBUF][ds][(mi * 16 + l15) * 32 + l4 * 8]; \
          _Pragma("unroll")                                                    \
          for (int nj2 = 0; nj2 < 2; ++nj2)                                    \
            accs[mi][nj2] = MFMA(ak, bq[nj2][ds], accs[mi][nj2]);              \
        }                                                                      \
    }
  #define PWRITE(PBUF)                                                         \
    {                                                                          \
      _Pragma("unroll")                                                        \
      for (int mi = 0; mi < 4; ++mi)                                           \
        _Pragma("unroll")                                                      \
        for (int nj2 = 0; nj2 < 2; ++nj2) {                                    \
          const int q = wave * 32 + nj2 * 16 + l15;                            \
          uint2 pk;                                                            \
          pk.x = pack_bf2(__builtin_amdgcn_exp2f(accs[mi][nj2][0]),            \
                          __builtin_amdgcn_exp2f(accs[mi][nj2][1]));           \
          pk.y = pack_bf2(__builtin_amdgcn_exp2f(accs[mi][nj2][2]),            \
                          __builtin_amdgcn_exp2f(accs[mi][nj2][3]));           \
          *(uint2*)&Psb[PBUF][mi >> 1][q * 40 + (mi & 1) * 16 + l4 * 4] = pk;  \
        }                                                                      \
    }
  #define OGEMM(PBUF, VBUF)                                                    \
    {                                                                          \
      _Pragma("unroll")                                                        \
      for (int ks = 0; ks < 2; ++ks)                                           \
        _Pragma("unroll")                                                      \
        for (int nj2 = 0; nj2 < 2; ++nj2) {                                    \
          bf16x8 ap = *(const bf16x8*)&Psb[PBUF][ks][(wave * 32 + nj2 * 16 + l15) * 40 + l4 * 8]; \
          _Pragma("unroll")                                                    \
          for (int nj = 0; nj < 4; ++nj) {                                     \
            bf16x8 bv = *(const bf16x8*)&Vsb[VBUF][ks][(nj * 16 + l15) * 32 + l4 * 8]; \
            acco[nj2][nj] = MFMA(ap, bv, acco[nj2][nj]);                       \
          }                                                                    \
        }                                                                      \
    }

  // prologue: iter 0 (S + P only)
  __syncthreads();                        // tile 0 staged
  {
    glds16(gK + (size_t)64 * E,      &Ksb[1][0][tid * 8]);   // prefetch tile 1
    glds16(gK + (size_t)64 * E + 32, &Ksb[1][1][tid * 8]);
    glds16(gV + 64,                  &Vsb[1][0][tid * 8]);
    glds16(gV + 64 + 32,             &Vsb[1][1][tid * 8]);
  }
  SGEMM(0);
  PWRITE(0);

  for (int it = 1; it < 16; ++it) {
    const int kc = it & 1, vb = it % 3;
    const int pp = (it - 1) & 1, vp = (it - 1) % 3;
    __syncthreads();                      // tile it staged; old buffers free
    if (it < 15) {
      const size_t kn = (size_t)(it + 1) * 64;
      glds16(gK + kn * E,      &Ksb[1 - kc][0][tid * 8]);
      glds16(gK + kn * E + 32, &Ksb[1 - kc][1][tid * 8]);
      glds16(gV + kn,          &Vsb[(it + 1) % 3][0][tid * 8]);
      glds16(gV + kn + 32,     &Vsb[(it + 1) % 3][1][tid * 8]);
    }
    SGEMM(kc);
    OGEMM(pp, vp);
    PWRITE(kc);
    (void)vb;
  }
  OGEMM(1, 0);   // epilogue: tile 15 (15&1=1, 15%3=0)

  #pragma unroll
  for (int nj2 = 0; nj2 < 2; ++nj2)
    #pragma unroll
    for (int nj = 0; nj < 4; ++nj)
      #pragma unroll
      for (int rr = 0; rr < 4; ++rr)
        O[(rowBase + q0 + wave * 32 + nj2 * 16 + l4 * 4 + rr) * E + h * 64 + nj * 16 + l15] =
            f2bf(acco[nj2][nj][rr]);
  #undef SGEMM
  #undef PWRITE
  #undef OGEMM
}

// ---------------------------------------------------------------------------
// inputs: 0=X 1=W_q 2=b_q 3=W_k 4=b_k 5=W_v 6=b_v 7=W_o 8=b_o
// ws (bf16): Xbf[4M] Wqkt[2M] Wot[1M] Qb[4M] Kb[4M] Ob[4M] Vt[4M]  (~46 MB)
// ---------------------------------------------------------------------------
extern "C" void kernel_launch(void* const* d_in, const int* in_sizes, int n_in,
                              void* d_out, int out_size, void* d_ws, size_t ws_size,
                              hipStream_t stream)
{
  const float* X  = (const float*)d_in[0];
  const float* Wq = (const float*)d_in[1];
  const float* bq = (const float*)d_in[2];
  const float* Wk = (const float*)d_in[3];
  const float* bk = (const float*)d_in[4];
  const float* Wo = (const float*)d_in[7];
  const float* bo = (const float*)d_in[8];

  const int Mr = 4096, E = 1024;
  unsigned short* Xbf  = (unsigned short*)d_ws;
  unsigned short* Wqkt = Xbf  + (size_t)Mr * E;
  unsigned short* Wot  = Wqkt + (size_t)2 * E * E;
  unsigned short* Qb   = Wot  + (size_t)E * E;
  unsigned short* Kb   = Qb   + (size_t)Mr * E;
  unsigned short* Ob   = Kb   + (size_t)Mr * E;
  unsigned short* Vt   = Ob   + (size_t)Mr * E;

  prep<<<dim3(4864), dim3(256), 0, stream>>>(X, Wq, Wk, Wo, Xbf, Wqkt, Wot);

  // fused Q|K' projection (K' = KEXC-scaled)
  gemm_m97<1><<<dim3(16, 32), dim3(256), 0, stream>>>(
      Xbf, Wqkt, bq, bk, (void*)Qb, (void*)Kb, 2048, E, KEXC);

  cs_vt<<<dim3(64, 16), dim3(256), 0, stream>>>(Qb, Kb, Vt);
  attn_out<<<dim3(64, 8), dim3(256), 0, stream>>>(Qb, Kb, Vt, Ob);

  gemm_m97<0><<<dim3(8, 32), dim3(256), 0, stream>>>(
      Ob, Wot, bo, nullptr, d_out, nullptr, E, E, 1.0f);
}

// Round 7
// 183.983 us; speedup vs baseline: 1.4635x; 1.0741x over previous
//
#include <hip/hip_runtime.h>
#include <cstddef>

typedef __attribute__((ext_vector_type(8))) short bf16x8;     // MFMA A/B frag
typedef __attribute__((ext_vector_type(4))) float f32x4;      // MFMA C/D frag
typedef __attribute__((ext_vector_type(8))) unsigned short us8;

#define MFMA(a, b, c) __builtin_amdgcn_mfma_f32_16x16x32_bf16((a), (b), (c), 0, 0, 0)

#define KEXC 0.0450842200277256f   // log2(e)/32  -> exp(s/32) = exp2(s*KEXC)

__device__ __forceinline__ unsigned short f2bf(float f) {   // RNE
  union { float f; unsigned int u; } v; v.f = f;
  return (unsigned short)((v.u + 0x7FFFu + ((v.u >> 16) & 1u)) >> 16);
}
__device__ __forceinline__ float bf2f(unsigned short u) {
  union { unsigned int u; float f; } v; v.u = ((unsigned int)u) << 16; return v.f;
}
// pack two floats to bf16 pair, round-half-up
__device__ __forceinline__ unsigned int pack_bf2(float a, float b) {
  union { float f; unsigned int u; } x, y; x.f = a; y.f = b;
  return ((x.u + 0x8000u) >> 16) | ((y.u + 0x8000u) & 0xFFFF0000u);
}
// async global->LDS, 16B/lane; LDS dest = wave-uniform base + lane*16
__device__ __forceinline__ void glds16(const void* g, void* l) {
  __builtin_amdgcn_global_load_lds(
      (const __attribute__((address_space(1))) unsigned int*)g,
      (__attribute__((address_space(3))) unsigned int*)l, 16, 0, 0);
}

// ---------------------------------------------------------------------------
// prep: blocks [0,4096): cast X fp32->bf16 (1024 elems/block).
//       blocks [4096,4864): transpose+cast weights -> Wt[N][K] bf16.
//         +0..255: Wq; +256..511: Wk (scaled KEXC); +512..767: Wo.
// ---------------------------------------------------------------------------
__global__ __launch_bounds__(256) void prep(
    const float* __restrict__ X,  const float* __restrict__ Wq,
    const float* __restrict__ Wk, const float* __restrict__ Wo,
    unsigned short* __restrict__ Xbf, unsigned short* __restrict__ Wqkt,
    unsigned short* __restrict__ Wot)
{
  __shared__ __align__(16) unsigned short T[64 * 72];
  const int t = threadIdx.x;
  int blk = blockIdx.x;
  if (blk < 4096) {
    int i = (blk * 256 + t) * 4;
    float4 v = *(const float4*)&X[i];
    ushort4 o;
    o.x = f2bf(v.x); o.y = f2bf(v.y); o.z = f2bf(v.z); o.w = f2bf(v.w);
    *(ushort4*)&Xbf[i] = o;
    return;
  }
  blk -= 4096;
  const float* W; unsigned short* dst; int mode; float scale = 1.0f;
  if (blk < 256)      { W = Wq; dst = Wqkt;                 mode = 1; }
  else if (blk < 512) { W = Wk; dst = Wqkt + 1024 * 1024;   mode = 1; scale = KEXC; blk -= 256; }
  else                { W = Wo; dst = Wot;                  mode = 0; blk -= 512; }
  const int K = 1024, N = 1024;
  const int n0 = (blk & 15) * 64, k0 = (blk >> 4) * 64;
  const int kr = t >> 4, n4 = (t & 15) * 4;
  #pragma unroll
  for (int i = 0; i < 4; ++i) {
    const int k = k0 + kr + i * 16;
    const float* src = (mode == 0) ? &W[(size_t)k * N + n0 + n4]
                                   : &W[((size_t)(n0 >> 6) * K + k) * 64 + n4];
    float4 v = *(const float4*)src;
    T[(n4 + 0) * 72 + kr + i * 16] = f2bf(v.x * scale);
    T[(n4 + 1) * 72 + kr + i * 16] = f2bf(v.y * scale);
    T[(n4 + 2) * 72 + kr + i * 16] = f2bf(v.z * scale);
    T[(n4 + 3) * 72 + kr + i * 16] = f2bf(v.w * scale);
  }
  __syncthreads();
  const int n = t >> 2, kc = (t & 3) * 16;
  us8 o0 = *(const us8*)&T[n * 72 + kc];
  us8 o1 = *(const us8*)&T[n * 72 + kc + 8];
  *(us8*)&dst[(size_t)(n0 + n) * K + k0 + kc] = o0;
  *(us8*)&dst[(size_t)(n0 + n) * K + k0 + kc + 8] = o1;
}

// ---------------------------------------------------------------------------
// gemm2: C[m,n] = sum_k A[m,k]*Bt[n,k] + bias.  128m x 64n tile, BK=64
// (two 32-k subtiles in [row][32] layout -> proven LDS bank behavior).
// 4 waves as 2x2 over (64m x 32n); 16 MFMA/wave/iter, 16 iters. LDS 24 KB.
// QK proj (SPLIT=1): 1024 blocks -> 4/CU.  Final (SPLIT=0): 512 -> 2/CU.
// SPLIT=1: N=2048, bf16 out; n-tile uniform: n0<1024 -> out0+bias0 else
//          out1+bias1*bs1.   SPLIT=0: fp32 out -> out0+bias0.
// Accumulation order over k identical to the 128x128/BK32 version.
// ---------------------------------------------------------------------------
template<int SPLIT>
__global__ __launch_bounds__(256) void gemm2(
    const unsigned short* __restrict__ A, const unsigned short* __restrict__ Bt,
    const float* __restrict__ bias0, const float* __restrict__ bias1,
    void* __restrict__ out0, void* __restrict__ out1, int N, int K, float bs1)
{
  __shared__ __align__(16) unsigned short Asl[2][128 * 32];
  __shared__ __align__(16) unsigned short Bsl[2][64 * 32];
  const int tid = threadIdx.x;
  const int m0 = blockIdx.y * 128, n0 = blockIdx.x * 64;
  const int wave = tid >> 6, lane = tid & 63;
  const int wm = (wave & 1) * 64, wn = (wave >> 1) * 32;
  const int l15 = lane & 15, l4 = lane >> 4;
  const int srow = tid >> 2, scol = (tid & 3) * 8;
  const unsigned short* ga = &A[(size_t)(m0 + srow) * K + scol];
  const unsigned short* gb = &Bt[(size_t)(n0 + srow) * K + scol];
  const size_t half = (size_t)64 * K;

  f32x4 acc[4][2] = {};
  for (int kt = 0; kt < K; kt += 64) {
    __syncthreads();                       // prior frag reads done
    #pragma unroll
    for (int ds = 0; ds < 2; ++ds) {
      glds16(ga + kt + ds * 32,        &Asl[ds][tid * 8]);
      glds16(ga + half + kt + ds * 32, &Asl[ds][(tid + 256) * 8]);
      glds16(gb + kt + ds * 32,        &Bsl[ds][tid * 8]);
    }
    __syncthreads();                       // staging complete
    #pragma unroll
    for (int ds = 0; ds < 2; ++ds) {
      bf16x8 af[4], bfv[2];
      #pragma unroll
      for (int mi = 0; mi < 4; ++mi)
        af[mi] = *(const bf16x8*)&Asl[ds][(wm + mi * 16 + l15) * 32 + l4 * 8];
      #pragma unroll
      for (int nj = 0; nj < 2; ++nj)
        bfv[nj] = *(const bf16x8*)&Bsl[ds][(wn + nj * 16 + l15) * 32 + l4 * 8];
      #pragma unroll
      for (int mi = 0; mi < 4; ++mi)
        #pragma unroll
        for (int nj = 0; nj < 2; ++nj)
          acc[mi][nj] = MFMA(af[mi], bfv[nj], acc[mi][nj]);
    }
  }

  const int qside = SPLIT ? (n0 < 1024) : 1;
  const float* bias = (SPLIT && !qside) ? bias1 : bias0;
  const float bscale = (SPLIT && !qside) ? bs1 : 1.0f;
  unsigned short* dstb = (SPLIT && !qside) ? (unsigned short*)out1 : (unsigned short*)out0;
  const int ncol0 = (SPLIT && !qside) ? n0 - 1024 : n0;
  #pragma unroll
  for (int mi = 0; mi < 4; ++mi) {
    #pragma unroll
    for (int nj = 0; nj < 2; ++nj) {
      const int row = m0 + wm + mi * 16 + l4 * 4;
      const int col = ncol0 + wn + nj * 16 + l15;
      const float bv = bias[col] * bscale;
      #pragma unroll
      for (int r = 0; r < 4; ++r) {
        const float v = acc[mi][nj][r] + bv;
        if (SPLIT) dstb[(size_t)(row + r) * 1024 + col] = f2bf(v);
        else       ((float*)out0)[(size_t)(row + r) * N + col] = v;
      }
    }
  }
}

// ---------------------------------------------------------------------------
// cs_vt: per (bh, k-tile64): L[k] = sum_q exp2(K'[k,:].Q[q,:]), then
//        Vt[bh*64+d][k] = Q[k,d]/L[k]  (bf16, k contiguous).
// K-frags resident in VGPRs; Q staged glds double-buffered; T aliases Q pool.
// LDS 32.25 KB -> 4 blocks/CU (grid 1024).
// ---------------------------------------------------------------------------
__global__ __launch_bounds__(256) void cs_vt(
    const unsigned short* __restrict__ Qb, const unsigned short* __restrict__ Kb,
    unsigned short* __restrict__ Vt)
{
  const int S = 1024, E = 1024;
  __shared__ __align__(16) unsigned short pool[16384];   // Qs[2][2][128*32]; T aliases
  __shared__ float Ls[64];
  const int bh = blockIdx.x, b = bh >> 4, h = bh & 15;
  const int k0 = blockIdx.y * 64;
  const int tid = threadIdx.x, wave = tid >> 6, lane = tid & 63;
  const int l15 = lane & 15, l4 = lane >> 4;
  const size_t rowBase = (size_t)b * S;
  const int srow = tid >> 2, scol = (tid & 3) * 8;
  const unsigned short* gQs = &Qb[(rowBase + srow) * E + h * 64 + scol];
  #define QS(buf, ds) (pool + (buf) * 8192 + (ds) * 4096)

  // resident K' A-frags for this wave's 16 k-rows (one-time global load)
  bf16x8 ak[2];
  #pragma unroll
  for (int ds = 0; ds < 2; ++ds)
    ak[ds] = *(const bf16x8*)&Kb[(rowBase + k0 + wave * 16 + l15) * E + h * 64 + ds * 32 + l4 * 8];

  #pragma unroll
  for (int ds = 0; ds < 2; ++ds) {
    glds16(gQs + (size_t)0 * E  + ds * 32, QS(0, ds) + tid * 8);
    glds16(gQs + (size_t)64 * E + ds * 32, QS(0, ds) + (tid + 256) * 8);
  }

  float Lacc[4] = {};
  for (int it = 0; it < 8; ++it) {
    const int cur = it & 1;
    __syncthreads();             // Qs[cur] staged; prior reads of Qs[1-cur] done
    if (it < 7) {
      const size_t q1 = (size_t)(it + 1) * 128;
      #pragma unroll
      for (int ds = 0; ds < 2; ++ds) {
        glds16(gQs + q1 * E        + ds * 32, QS(1 - cur, ds) + tid * 8);
        glds16(gQs + (q1 + 64) * E + ds * 32, QS(1 - cur, ds) + (tid + 256) * 8);
      }
    }
    f32x4 accs[8] = {};
    #pragma unroll
    for (int ds = 0; ds < 2; ++ds)
      #pragma unroll
      for (int nj = 0; nj < 8; ++nj) {
        bf16x8 bv = *(const bf16x8*)&QS(cur, ds)[(nj * 16 + l15) * 32 + l4 * 8];
        accs[nj] = MFMA(ak[ds], bv, accs[nj]);
      }
    #pragma unroll
    for (int nj = 0; nj < 8; ++nj)
      #pragma unroll
      for (int rr = 0; rr < 4; ++rr)
        Lacc[rr] += __builtin_amdgcn_exp2f(accs[nj][rr]);
  }
  #pragma unroll
  for (int off = 1; off < 16; off <<= 1)
    #pragma unroll
    for (int rr = 0; rr < 4; ++rr)
      Lacc[rr] += __shfl_xor(Lacc[rr], off);
  if (l15 == 0) {
    #pragma unroll
    for (int rr = 0; rr < 4; ++rr)
      Ls[wave * 16 + l4 * 4 + rr] = Lacc[rr];
  }
  __syncthreads();   // Ls ready; all Qs reads done -> pool reusable as T

  unsigned short* T = pool;   // 64*72 = 4608 ushorts
  const int row = tid >> 2, d16 = (tid & 3) * 16;
  const float rl = 1.0f / Ls[row];
  const unsigned short* src = &Qb[(rowBase + k0 + row) * E + h * 64 + d16];
  us8 v0 = *(const us8*)src, v1 = *(const us8*)(src + 8);
  #pragma unroll
  for (int j = 0; j < 8; ++j) T[(d16 + j) * 72 + row]     = f2bf(bf2f(v0[j]) * rl);
  #pragma unroll
  for (int j = 0; j < 8; ++j) T[(d16 + 8 + j) * 72 + row] = f2bf(bf2f(v1[j]) * rl);
  __syncthreads();
  const int d = tid >> 2, kh = (tid & 3) * 16;
  unsigned short* dst = &Vt[((size_t)bh * 64 + d) * S + k0 + kh];
  *(us8*)dst       = *(const us8*)&T[d * 72 + kh];
  *(us8*)(dst + 8) = *(const us8*)&T[d * 72 + kh + 8];
  #undef QS
}

// ---------------------------------------------------------------------------
// attn_out: per (bh, q-tile128): stream 16 k-tiles of 64, software-pipelined:
//   iter it:  S-GEMM(it) -> O-GEMM(it-1) -> exp2/write Ps(it)
// Ps double-buffered (write->read distance = 1 iter, wave-private, no
// barrier), Vs triple-buffered, Ks double-buffered. Ps row stride 40 ushorts.
// Q-frags resident in VGPRs. One barrier/iter. LDS 80 KB -> 2 blocks/CU.
// grid(x=64 bh, y=8 qtile) -> same-bh blocks share an XCD (ids 64 apart).
// ---------------------------------------------------------------------------
__global__ __launch_bounds__(256) void attn_out(
    const unsigned short* __restrict__ Qb, const unsigned short* __restrict__ Kb,
    const unsigned short* __restrict__ VtH, unsigned short* __restrict__ O)
{
  const int S = 1024, E = 1024;
  __shared__ __align__(16) unsigned short Ksb[2][2][64 * 32];   // [buf][dhalf]
  __shared__ __align__(16) unsigned short Vsb[3][2][64 * 32];   // [buf][khalf]
  __shared__ __align__(16) unsigned short Psb[2][2][128 * 40];  // [buf][khalf]
  const int bh = blockIdx.x, b = bh >> 4, h = bh & 15;
  const int q0 = blockIdx.y * 128;
  const int tid = threadIdx.x, wave = tid >> 6, lane = tid & 63;
  const int l15 = lane & 15, l4 = lane >> 4;
  const size_t rowBase = (size_t)b * S;
  const int srow = tid >> 2, scol = (tid & 3) * 8;
  const unsigned short* gK = &Kb[(rowBase + srow) * E + h * 64 + scol];
  const unsigned short* gV = &VtH[((size_t)bh * 64 + srow) * S + scol];

  // resident Q B-frags: q = wave*32 + nj2*16 + l15
  bf16x8 bq[2][2];
  #pragma unroll
  for (int nj2 = 0; nj2 < 2; ++nj2)
    #pragma unroll
    for (int ds = 0; ds < 2; ++ds)
      bq[nj2][ds] = *(const bf16x8*)&Qb[(rowBase + q0 + wave * 32 + nj2 * 16 + l15) * E
                                        + h * 64 + ds * 32 + l4 * 8];

  // stage tile 0
  glds16(gK,      &Ksb[0][0][tid * 8]);
  glds16(gK + 32, &Ksb[0][1][tid * 8]);
  glds16(gV,      &Vsb[0][0][tid * 8]);
  glds16(gV + 32, &Vsb[0][1][tid * 8]);

  f32x4 acco[2][4] = {};
  f32x4 accs[4][2];

  #define SGEMM(KBUF)                                                          \
    {                                                                          \
      _Pragma("unroll")                                                        \
      for (int mi = 0; mi < 4; ++mi)                                           \
        _Pragma("unroll")                                                      \
        for (int nj2 = 0; nj2 < 2; ++nj2) accs[mi][nj2] = (f32x4){};           \
      _Pragma("unroll")                                                        \
      for (int ds = 0; ds < 2; ++ds)                                           \
        _Pragma("unroll")                                                      \
        for (int mi = 0; mi < 4; ++mi) {                                       \
          bf16x8 ak = *(const bf16x8*)&Ksb[KBUF][ds][(mi * 16 + l15) * 32 + l4 * 8]; \
          _Pragma("unroll")                                                    \
          for (int nj2 = 0; nj2 < 2; ++nj2)                                    \
            accs[mi][nj2] = MFMA(ak, bq[nj2][ds], accs[mi][nj2]);              \
        }                                                                      \
    }
  #define PWRITE(PBUF)                                                         \
    {                                                                          \
      _Pragma("unroll")                                                        \
      for (int mi = 0; mi < 4; ++mi)                                           \
        _Pragma("unroll")                                                      \
        for (int nj2 = 0; nj2 < 2; ++nj2) {                                    \
          const int q = wave * 32 + nj2 * 16 + l15;                            \
          uint2 pk;                                                            \
          pk.x = pack_bf2(__builtin_amdgcn_exp2f(accs[mi][nj2][0]),            \
                          __builtin_amdgcn_exp2f(accs[mi][nj2][1]));           \
          pk.y = pack_bf2(__builtin_amdgcn_exp2f(accs[mi][nj2][2]),            \
                          __builtin_amdgcn_exp2f(accs[mi][nj2][3]));           \
          *(uint2*)&Psb[PBUF][mi >> 1][q * 40 + (mi & 1) * 16 + l4 * 4] = pk;  \
        }                                                                      \
    }
  #define OGEMM(PBUF, VBUF)                                                    \
    {                                                                          \
      _Pragma("unroll")                                                        \
      for (int ks = 0; ks < 2; ++ks)                                           \
        _Pragma("unroll")                                                      \
        for (int nj2 = 0; nj2 < 2; ++nj2) {                                    \
          bf16x8 ap = *(const bf16x8*)&Psb[PBUF][ks][(wave * 32 + nj2 * 16 + l15) * 40 + l4 * 8]; \
          _Pragma("unroll")                                                    \
          for (int nj = 0; nj < 4; ++nj) {                                     \
            bf16x8 bv = *(const bf16x8*)&Vsb[VBUF][ks][(nj * 16 + l15) * 32 + l4 * 8]; \
            acco[nj2][nj] = MFMA(ap, bv, acco[nj2][nj]);                       \
          }                                                                    \
        }                                                                      \
    }

  // prologue: iter 0 (S + P only)
  __syncthreads();                        // tile 0 staged
  {
    glds16(gK + (size_t)64 * E,      &Ksb[1][0][tid * 8]);   // prefetch tile 1
    glds16(gK + (size_t)64 * E + 32, &Ksb[1][1][tid * 8]);
    glds16(gV + 64,                  &Vsb[1][0][tid * 8]);
    glds16(gV + 64 + 32,             &Vsb[1][1][tid * 8]);
  }
  SGEMM(0);
  PWRITE(0);

  for (int it = 1; it < 16; ++it) {
    const int kc = it & 1;
    const int pp = (it - 1) & 1, vp = (it - 1) % 3;
    __syncthreads();                      // tile it staged; old buffers free
    if (it < 15) {
      const size_t kn = (size_t)(it + 1) * 64;
      glds16(gK + kn * E,      &Ksb[1 - kc][0][tid * 8]);
      glds16(gK + kn * E + 32, &Ksb[1 - kc][1][tid * 8]);
      glds16(gV + kn,          &Vsb[(it + 1) % 3][0][tid * 8]);
      glds16(gV + kn + 32,     &Vsb[(it + 1) % 3][1][tid * 8]);
    }
    SGEMM(kc);
    OGEMM(pp, vp);
    PWRITE(kc);
  }
  OGEMM(1, 0);   // epilogue: tile 15 (15&1=1, 15%3=0)

  #pragma unroll
  for (int nj2 = 0; nj2 < 2; ++nj2)
    #pragma unroll
    for (int nj = 0; nj < 4; ++nj)
      #pragma unroll
      for (int rr = 0; rr < 4; ++rr)
        O[(rowBase + q0 + wave * 32 + nj2 * 16 + l4 * 4 + rr) * E + h * 64 + nj * 16 + l15] =
            f2bf(acco[nj2][nj][rr]);
  #undef SGEMM
  #undef PWRITE
  #undef OGEMM
}

// ---------------------------------------------------------------------------
// inputs: 0=X 1=W_q 2=b_q 3=W_k 4=b_k 5=W_v 6=b_v 7=W_o 8=b_o
// ws (bf16): Xbf[4M] Wqkt[2M] Wot[1M] Qb[4M] Kb[4M] Ob[4M] Vt[4M]  (~46 MB)
// ---------------------------------------------------------------------------
extern "C" void kernel_launch(void* const* d_in, const int* in_sizes, int n_in,
                              void* d_out, int out_size, void* d_ws, size_t ws_size,
                              hipStream_t stream)
{
  const float* X  = (const float*)d_in[0];
  const float* Wq = (const float*)d_in[1];
  const float* bq = (const float*)d_in[2];
  const float* Wk = (const float*)d_in[3];
  const float* bk = (const float*)d_in[4];
  const float* Wo = (const float*)d_in[7];
  const float* bo = (const float*)d_in[8];

  const int Mr = 4096, E = 1024;
  unsigned short* Xbf  = (unsigned short*)d_ws;
  unsigned short* Wqkt = Xbf  + (size_t)Mr * E;
  unsigned short* Wot  = Wqkt + (size_t)2 * E * E;
  unsigned short* Qb   = Wot  + (size_t)E * E;
  unsigned short* Kb   = Qb   + (size_t)Mr * E;
  unsigned short* Ob   = Kb   + (size_t)Mr * E;
  unsigned short* Vt   = Ob   + (size_t)Mr * E;

  prep<<<dim3(4864), dim3(256), 0, stream>>>(X, Wq, Wk, Wo, Xbf, Wqkt, Wot);

  // fused Q|K' projection (K' = KEXC-scaled): 128x64 tiles -> 1024 blocks (4/CU)
  gemm2<1><<<dim3(32, 32), dim3(256), 0, stream>>>(
      Xbf, Wqkt, bq, bk, (void*)Qb, (void*)Kb, 2048, E, KEXC);

  cs_vt<<<dim3(64, 16), dim3(256), 0, stream>>>(Qb, Kb, Vt);
  attn_out<<<dim3(64, 8), dim3(256), 0, stream>>>(Qb, Kb, Vt, Ob);

  // final projection: 128x64 tiles -> 512 blocks (2/CU)
  gemm2<0><<<dim3(16, 32), dim3(256), 0, stream>>>(
      Ob, Wot, bo, nullptr, d_out, nullptr, E, E, 1.0f);
}